// Round 13
// baseline (230.674 us; speedup 1.0000x reference)
//
#include <hip/hip_runtime.h>
#include <stdint.h>

// Hard voxelization, MI355X. f32x4 points -> f32 concat out:
//   voxels[60000,32,4], coors[60000,3](z,y,x), npv[60000], voxel_num[1].
//
// Settled forensics (R5-R12):
//  - k_build ~47us = one 64B-line device-scope atomic per voxel through the
//    coherence point (~1.4TB/s scattered-line ceiling). ILP-proof (R7);
//    alpha-sensitive (R11: alpha .84 doubled traffic; R12: alpha .42 optimal).
//  - Mid-pipeline must be 1 pt/thread (R10: ITEMS loops = grid-starved latency).
//  - Reads are L3-absorbed; only scattered atomic WRITES reach the counter.
//  - Harness tax (~60us: 256MB ws re-poison + in/out restore) is immovable.
// R13: flags+scan merged via last-block ticket (-1 launch); contested bitmask
// (init 1.2MB->150KB, broadcast reads).

#define GX 1024
#define GY 1024
#define GZ 40
#define MAXV 60000
#define MAXP 32
#define HBITS 21
#define HSIZE (1u << HBITS)
#define HMASK (HSIZE - 1u)
#define CANDBIT (1 << 30)
#define FLATMASK (CANDBIT - 1)
#define TB 256
#define MAXIP 20            // scan items/thread cap (n <= 1.31M)
#define EMPTY64 0xFFFFFFFFFFFFFFFFull

#define OFF_COORS ((size_t)MAXV * MAXP * 4)            // 7,680,000
#define OFF_NPV   (OFF_COORS + (size_t)MAXV * 3)       // 7,860,000
#define OFF_VNUM  (OFF_NPV + (size_t)MAXV)             // 7,920,000

typedef unsigned long long u64;

__device__ __forceinline__ unsigned hashf(int flat) {
    return ((unsigned)flat * 2654435761u) >> (32 - HBITS);
}

// ---- init: h64=EMPTY(16MB), cbits=0, dupcnt=0, repidx=-1, coors=0, done=0 ----
__global__ void k_init(u64* __restrict__ h64, u64* __restrict__ cbits,
                       int* __restrict__ dupcnt, int* __restrict__ repidx,
                       int* __restrict__ done, int n, float* __restrict__ oF) {
    int i = blockIdx.x * blockDim.x + threadIdx.x;
    int stride = gridDim.x * blockDim.x;
    for (int j = i; j < (int)HSIZE; j += stride) h64[j] = EMPTY64;
    int ncw = (n + 63) / 64;
    for (int j = i; j < ncw; j += stride) cbits[j] = 0;
    for (int j = i; j < MAXV; j += stride) { dupcnt[j] = 0; repidx[j] = -1; }
    for (int j = i; j < MAXV * 3; j += stride) oF[OFF_COORS + j] = 0.f;
    if (i == 0) *done = 0;
}

__device__ __forceinline__ int voxel_flat(float4 pt) {
    // identical IEEE f32 math to reference
    float fx = floorf((pt.x + 51.2f) / 0.1f);
    float fy = floorf((pt.y + 51.2f) / 0.1f);
    float fz = floorf((pt.z + 5.0f) / 0.2f);
    int cx = (int)fx, cy = (int)fy, cz = (int)fz;
    bool valid = (fx >= 0.f) & (cx < GX) & (fy >= 0.f) & (cy < GY) & (fz >= 0.f) & (cz < GZ);
    return valid ? (cx * GY + cy) * GZ + cz : -1;
}

// ---- build: 1 CAS typ.; pflat = flat | CANDBIT(candidate), -1 invalid ----
__global__ __launch_bounds__(TB) void k_build(const float4* __restrict__ pts, int n,
                                              u64* __restrict__ h64,
                                              int* __restrict__ pflat,
                                              u64* __restrict__ cbits) {
    int p = blockIdx.x * blockDim.x + threadIdx.x;
    if (p >= n) return;
    float4 pt = pts[p];
    int flat = voxel_flat(pt);
    if (flat < 0) { pflat[p] = -1; return; }
    u64 want = ((u64)(unsigned)flat << 32) | (unsigned)p;
    unsigned slot = hashf(flat);
    int cand = 0;
    for (int probe = 0; probe < 4096; probe++) {          // bounded: hang-proof
        u64 cur = atomicCAS(&h64[slot], EMPTY64, want);
        if (cur == EMPTY64) { cand = 1; break; }          // insert winner
        if ((unsigned)(cur >> 32) == (unsigned)flat) {    // existing voxel
            if ((unsigned)cur > (unsigned)p) {
                u64 old = atomicMin(&h64[slot], want);    // key equal -> compares rep
                unsigned oldrep = (unsigned)old;
                if (oldrep > (unsigned)p) {               // we really lowered it
                    atomicOr(&cbits[oldrep >> 6], 1ull << (oldrep & 63));
                    cand = 1;                             // prev holder dethroned
                }
            }
            break;
        }
        slot = (slot + 1u) & HMASK;
    }
    pflat[p] = flat | (cand ? CANDBIT : 0);
}

// ---- flagscan: ballot flags + block sums; last-finishing block scans ----
__global__ __launch_bounds__(TB) void k_flagscan(const int* __restrict__ pflat,
                                                 const u64* __restrict__ cbits,
                                                 int n, u64* __restrict__ flagbits,
                                                 int* __restrict__ partials,
                                                 int* __restrict__ done, int nb,
                                                 float* __restrict__ oF) {
    __shared__ int ws[4];
    __shared__ int ticket;
    __shared__ int sh[TB];
    int b = blockIdx.x, t = threadIdx.x;
    int i = b * TB + t;
    int pred = 0;
    if (i < n) {
        int pf = pflat[i];
        pred = (pf >= 0) && (pf & CANDBIT) && !((cbits[i >> 6] >> (i & 63)) & 1ull);
    }
    u64 m = __ballot(pred);
    int w = t >> 6, lane = t & 63;
    if (lane == 0) { flagbits[b * 4 + w] = m; ws[w] = __popcll(m); }
    __syncthreads();
    if (t == 0) {
        partials[b] = ws[0] + ws[1] + ws[2] + ws[3];
        __threadfence();                            // partials[b] visible first
        ticket = atomicAdd(done, 1);
    }
    __syncthreads();
    if (ticket != nb - 1) return;                   // not last: done
    __threadfence();
    int IP = (nb + TB - 1) / TB;                    // 19 for nb=4688
    if (IP > MAXIP) IP = MAXIP;
    int base = t * IP;
    int v[MAXIP];
    int s = 0;
    for (int k = 0; k < IP; k++) {
        int idx = base + k;
        int x = (idx < nb) ? partials[idx] : 0;
        v[k] = x; s += x;
    }
    sh[t] = s;
    __syncthreads();
    for (int off = 1; off < TB; off <<= 1) {
        int add = (t >= off) ? sh[t - off] : 0;
        __syncthreads();
        sh[t] += add;
        __syncthreads();
    }
    int run = sh[t] - s;                            // exclusive base
    for (int k = 0; k < IP; k++) {
        int idx = base + k;
        if (idx < nb) partials[idx] = run;
        run += v[k];
    }
    if (t == TB - 1) {
        int total = sh[TB - 1];
        if (total > MAXV) total = MAXV;
        oF[OFF_VNUM] = (float)total;                // voxel_num
    }
}

// ---- finish: 1 pt/thread; vid via popcount rank; reps->coors/repidx,
//      dups(~9K)->h64 re-probe + rank -> dupcnt/list ----
__global__ __launch_bounds__(TB) void k_finish(const u64* __restrict__ flagbits,
                                               const int* __restrict__ partials,
                                               const int* __restrict__ pflat,
                                               const u64* __restrict__ h64,
                                               int* __restrict__ repidx,
                                               int* __restrict__ dupcnt,
                                               int* __restrict__ list, int n,
                                               float* __restrict__ oF) {
    int b = blockIdx.x, t = threadIdx.x;
    int i = b * TB + t;
    if (i >= n) return;
    int lane = t & 63, w = t >> 6;
    u64 w0 = flagbits[b * 4 + 0];
    u64 w1 = flagbits[b * 4 + 1];
    u64 w2 = flagbits[b * 4 + 2];
    u64 w3 = flagbits[b * 4 + 3];
    u64 myw = (w == 0) ? w0 : (w == 1) ? w1 : (w == 2) ? w2 : w3;
    int bit = (int)((myw >> lane) & 1);
    int pf = pflat[i];
    if (bit) {                                           // first occurrence (rep)
        int wbase = (w > 0 ? __popcll(w0) : 0) + (w > 1 ? __popcll(w1) : 0)
                  + (w > 2 ? __popcll(w2) : 0);
        int vid = partials[b] + wbase + (int)__popcll(myw & ((1ull << lane) - 1ull));
        if (vid < MAXV) {
            int flat = pf & FLATMASK;
            int zc = flat % GZ;
            int t2 = flat / GZ;
            int yc = t2 % GY;
            int xc = t2 / GY;
            size_t cOff = OFF_COORS + (size_t)vid * 3;
            oF[cOff + 0] = (float)zc;
            oF[cOff + 1] = (float)yc;
            oF[cOff + 2] = (float)xc;
            repidx[vid] = i;
        }
    } else if (pf >= 0) {                                // non-rep valid (~9K)
        int flat = pf & FLATMASK;
        unsigned slot = hashf(flat);
        unsigned rep = 0xFFFFFFFFu;
        for (int probe = 0; probe < 4096; probe++) {     // read-only, L3-hot
            u64 cur = h64[slot];
            if ((unsigned)(cur >> 32) == (unsigned)flat) { rep = (unsigned)cur; break; }
            if (cur == EMPTY64) break;
            slot = (slot + 1u) & HMASK;
        }
        if (rep != 0xFFFFFFFFu) {
            int br = (int)(rep >> 8);                    // rep's 256-block
            int lb = (int)(rep & 255u);
            int dvid = partials[br];
            int wb = br * 4, nw = lb >> 6;
            for (int q = 0; q < nw; q++) dvid += (int)__popcll(flagbits[wb + q]);
            int tail = lb & 63;
            if (tail) dvid += (int)__popcll(flagbits[wb + nw] & ((1ull << tail) - 1ull));
            if (dvid < MAXV) {
                int pos = atomicAdd(&dupcnt[dvid], 1);
                if (pos < MAXP - 1) list[dvid * (MAXP - 1) + pos] = i;
            }
        }
    }
}

// ---- emit: thread-per-row, fully coalesced voxels store; npv ----
__global__ __launch_bounds__(TB) void k_emit(const float4* __restrict__ pts,
                                             const int* __restrict__ repidx,
                                             const int* __restrict__ dupcnt,
                                             const int* __restrict__ list,
                                             float4* __restrict__ outVox,
                                             float* __restrict__ oF) {
    int gid = blockIdx.x * TB + threadIdx.x;
    int vid = gid >> 5;
    if (vid >= MAXV) return;
    int r = gid & 31;
    int ri = repidx[vid];
    int dc = dupcnt[vid];
    int d = dc < (MAXP - 1) ? dc : (MAXP - 1);
    int m = (ri >= 0) ? (1 + d) : 0;
    if (r == 0) oF[OFF_NPV + vid] = (float)m;
    float4 row = make_float4(0.f, 0.f, 0.f, 0.f);
    if (r == 0 && m > 0) {
        row = pts[ri];                               // rep = provably min index
    } else if (r < m) {                              // dup rows, ascending index
        const int* lst = &list[vid * (MAXP - 1)];
        int target = r - 1, pick = -1;
        for (int a = 0; a < d; a++) {
            int e = lst[a];
            int rk = 0;
            for (int bq = 0; bq < d; bq++) rk += (lst[bq] < e);
            if (rk == target) pick = e;
        }
        row = pts[pick];
    }
    outVox[(size_t)vid * MAXP + r] = row;            // coalesced 16B x 64 lanes
}

extern "C" void kernel_launch(void* const* d_in, const int* in_sizes, int n_in,
                              void* d_out, int out_size, void* d_ws, size_t ws_size,
                              hipStream_t stream) {
    int n = in_sizes[0] / 4;                       // 1,200,000
    const float4* pts = (const float4*)d_in[0];

    int tb = TB;
    int nbp = (n + tb - 1) / tb;                   // 4688 (1 pt/thread grids)
    int nwords = nbp * 4;                          // flag words (4 per block)
    int ncw = (n + 63) / 64;                       // contested words

    // ws layout, ~29 MB
    char* base = (char*)d_ws;
    size_t o = 0;
    int* partials = (int*)(base + o);  o += ((size_t)nbp * 4 + 255) & ~(size_t)255;
    int* done     = (int*)(base + o);  o += 256;
    int* dupcnt   = (int*)(base + o);  o += (size_t)MAXV * 4;
    int* repidx   = (int*)(base + o);  o += (size_t)MAXV * 4;
    o = (o + 255) & ~(size_t)255;
    u64* flagbits = (u64*)(base + o);  o += (size_t)nwords * 8;
    o = (o + 255) & ~(size_t)255;
    u64* cbits    = (u64*)(base + o);  o += ((size_t)ncw * 8 + 255) & ~(size_t)255;
    u64* h64      = (u64*)(base + o);  o += (size_t)HSIZE * 8;
    int* pflat    = (int*)(base + o);  o += (size_t)n * 4;
    int* list     = (int*)(base + o);  o += (size_t)MAXV * (MAXP - 1) * 4;

    float* oF = (float*)d_out;

    k_init<<<2048, tb, 0, stream>>>(h64, cbits, dupcnt, repidx, done, n, oF);
    k_build<<<nbp, tb, 0, stream>>>(pts, n, h64, pflat, cbits);
    k_flagscan<<<nbp, tb, 0, stream>>>(pflat, cbits, n, flagbits, partials, done, nbp, oF);
    k_finish<<<nbp, tb, 0, stream>>>(flagbits, partials, pflat, h64, repidx, dupcnt, list, n, oF);
    k_emit<<<(MAXV * MAXP + tb - 1) / tb, tb, 0, stream>>>(pts, repidx, dupcnt, list,
                                                           (float4*)d_out, oF);
}

// Round 14
// 145.369 us; speedup vs baseline: 1.5868x; 1.5868x over previous
//
#include <hip/hip_runtime.h>
#include <stdint.h>

// Hard voxelization, MI355X. f32x4 points -> f32 concat out:
//   voxels[60000,32,4], coors[60000,3](z,y,x), npv[60000], voxel_num[1].
//
// Settled forensics (R5-R13):
//  - k_build = one 64B-line device-scope atomic per voxel via coherence point
//    (~1.4TB/s scattered-line ceiling; ILP-proof R7; alpha-sensitive R11/R12).
//  - Failed probe CASes dirty lines too (R11) -> R14 probes with plain reads
//    (cache-absorbed) and CASes only read-EMPTY slots. Staleness-safe: keys
//    write-once; rep monotone decreasing; stale-EMPTY re-verified by CAS.
//  - Mid-pipeline: 1 pt/thread only (R10: serial loops = grid starvation).
//  - NO grid-scale same-line atomics (R13: 4688-block ticket = 104us @22ns/RMW).
//  - Harness tax (~60us re-poison/restore) immovable.

#define GX 1024
#define GY 1024
#define GZ 40
#define MAXV 60000
#define MAXP 32
#define HBITS 21
#define HSIZE (1u << HBITS)
#define HMASK (HSIZE - 1u)
#define CANDBIT (1 << 30)
#define FLATMASK (CANDBIT - 1)
#define TB 256
#define EMPTY64 0xFFFFFFFFFFFFFFFFull

#define OFF_COORS ((size_t)MAXV * MAXP * 4)            // 7,680,000
#define OFF_NPV   (OFF_COORS + (size_t)MAXV * 3)       // 7,860,000
#define OFF_VNUM  (OFF_NPV + (size_t)MAXV)             // 7,920,000

typedef unsigned long long u64;

__device__ __forceinline__ unsigned hashf(int flat) {
    return ((unsigned)flat * 2654435761u) >> (32 - HBITS);
}

// ---- init: h64=EMPTY(16MB), cbits=0, dupcnt=0, repidx=-1, coors=0 ----
__global__ void k_init(u64* __restrict__ h64, u64* __restrict__ cbits,
                       int* __restrict__ dupcnt, int* __restrict__ repidx,
                       int n, float* __restrict__ oF) {
    int i = blockIdx.x * blockDim.x + threadIdx.x;
    int stride = gridDim.x * blockDim.x;
    for (int j = i; j < (int)HSIZE; j += stride) h64[j] = EMPTY64;
    int ncw = (n + 63) / 64;
    for (int j = i; j < ncw; j += stride) cbits[j] = 0;
    for (int j = i; j < MAXV; j += stride) { dupcnt[j] = 0; repidx[j] = -1; }
    for (int j = i; j < MAXV * 3; j += stride) oF[OFF_COORS + j] = 0.f;
}

__device__ __forceinline__ int voxel_flat(float4 pt) {
    // identical IEEE f32 math to reference
    float fx = floorf((pt.x + 51.2f) / 0.1f);
    float fy = floorf((pt.y + 51.2f) / 0.1f);
    float fz = floorf((pt.z + 5.0f) / 0.2f);
    int cx = (int)fx, cy = (int)fy, cz = (int)fz;
    bool valid = (fx >= 0.f) & (cx < GX) & (fy >= 0.f) & (cy < GY) & (fz >= 0.f) & (cz < GZ);
    return valid ? (cx * GY + cy) * GZ + cz : -1;
}

// ---- build: read-first probe; CAS only on read-EMPTY; min only on key-match ----
__global__ __launch_bounds__(TB) void k_build(const float4* __restrict__ pts, int n,
                                              u64* __restrict__ h64,
                                              int* __restrict__ pflat,
                                              u64* __restrict__ cbits) {
    int p = blockIdx.x * blockDim.x + threadIdx.x;
    if (p >= n) return;
    float4 pt = pts[p];
    int flat = voxel_flat(pt);
    if (flat < 0) { pflat[p] = -1; return; }
    u64 want = ((u64)(unsigned)flat << 32) | (unsigned)p;
    unsigned slot = hashf(flat);
    int cand = 0;
    for (int probe = 0; probe < 4096; probe++) {          // bounded: hang-proof
        u64 cur = h64[slot];                              // plain read (cache-absorbed)
        if (cur == EMPTY64) {
            cur = atomicCAS(&h64[slot], EMPTY64, want);   // authoritative
            if (cur == EMPTY64) { cand = 1; break; }      // insert winner
        }
        if ((unsigned)(cur >> 32) == (unsigned)flat) {    // existing voxel (key immutable)
            if ((unsigned)cur > (unsigned)p) {            // stale rep >= true rep: safe
                u64 old = atomicMin(&h64[slot], want);    // key equal -> compares rep
                unsigned oldrep = (unsigned)old;
                if (oldrep > (unsigned)p) {               // we really lowered it
                    atomicOr(&cbits[oldrep >> 6], 1ull << (oldrep & 63));
                    cand = 1;                             // prev holder dethroned
                }
            }
            break;
        }
        slot = (slot + 1u) & HMASK;
    }
    pflat[p] = flat | (cand ? CANDBIT : 0);
}

// ---- flags: 1 pt/thread; ballot -> flag words + block sums. No loops. ----
__global__ __launch_bounds__(TB) void k_flags(const int* __restrict__ pflat,
                                              const u64* __restrict__ cbits,
                                              int n, u64* __restrict__ flagbits,
                                              int* __restrict__ partials) {
    __shared__ int ws[4];
    int b = blockIdx.x, t = threadIdx.x;
    int i = b * TB + t;
    int pred = 0;
    if (i < n) {
        int pf = pflat[i];
        pred = (pf >= 0) && (pf & CANDBIT) && !((cbits[i >> 6] >> (i & 63)) & 1ull);
    }
    u64 m = __ballot(pred);
    int w = t >> 6, lane = t & 63;
    if (lane == 0) { flagbits[b * 4 + w] = m; ws[w] = __popcll(m); }
    __syncthreads();
    if (t == 0) partials[b] = ws[0] + ws[1] + ws[2] + ws[3];
}

// ---- scan: one 1024-thread block, 5 partials/thread -> exclusive offsets ----
__global__ __launch_bounds__(1024) void k_scan(int* __restrict__ partials, int npart,
                                               float* __restrict__ oF) {
    __shared__ int sh[1024];
    int t = threadIdx.x;
    int v[5];
    int s = 0;
    #pragma unroll
    for (int k = 0; k < 5; k++) {
        int idx = t * 5 + k;
        v[k] = (idx < npart) ? partials[idx] : 0;
        s += v[k];
    }
    sh[t] = s;
    __syncthreads();
    for (int off = 1; off < 1024; off <<= 1) {
        int add = (t >= off) ? sh[t - off] : 0;
        __syncthreads();
        sh[t] += add;
        __syncthreads();
    }
    int run = sh[t] - s;                     // exclusive base for this thread
    #pragma unroll
    for (int k = 0; k < 5; k++) {
        int idx = t * 5 + k;
        if (idx < npart) partials[idx] = run;
        run += v[k];
    }
    if (t == 1023) {
        int total = sh[1023];
        if (total > MAXV) total = MAXV;
        oF[OFF_VNUM] = (float)total;         // voxel_num
    }
}

// ---- finish: 1 pt/thread; vid via popcount rank; reps->coors/repidx,
//      dups(~7K)->h64 re-probe + rank -> dupcnt/list ----
__global__ __launch_bounds__(TB) void k_finish(const u64* __restrict__ flagbits,
                                               const int* __restrict__ partials,
                                               const int* __restrict__ pflat,
                                               const u64* __restrict__ h64,
                                               int* __restrict__ repidx,
                                               int* __restrict__ dupcnt,
                                               int* __restrict__ list, int n,
                                               float* __restrict__ oF) {
    int b = blockIdx.x, t = threadIdx.x;
    int i = b * TB + t;
    if (i >= n) return;
    int lane = t & 63, w = t >> 6;
    u64 w0 = flagbits[b * 4 + 0];
    u64 w1 = flagbits[b * 4 + 1];
    u64 w2 = flagbits[b * 4 + 2];
    u64 w3 = flagbits[b * 4 + 3];
    u64 myw = (w == 0) ? w0 : (w == 1) ? w1 : (w == 2) ? w2 : w3;
    int bit = (int)((myw >> lane) & 1);
    int pf = pflat[i];
    if (bit) {                                           // first occurrence (rep)
        int wbase = (w > 0 ? __popcll(w0) : 0) + (w > 1 ? __popcll(w1) : 0)
                  + (w > 2 ? __popcll(w2) : 0);
        int vid = partials[b] + wbase + (int)__popcll(myw & ((1ull << lane) - 1ull));
        if (vid < MAXV) {
            int flat = pf & FLATMASK;
            int zc = flat % GZ;
            int t2 = flat / GZ;
            int yc = t2 % GY;
            int xc = t2 / GY;
            size_t cOff = OFF_COORS + (size_t)vid * 3;
            oF[cOff + 0] = (float)zc;
            oF[cOff + 1] = (float)yc;
            oF[cOff + 2] = (float)xc;
            repidx[vid] = i;
        }
    } else if (pf >= 0) {                                // non-rep valid (~7K)
        int flat = pf & FLATMASK;
        unsigned slot = hashf(flat);
        unsigned rep = 0xFFFFFFFFu;
        for (int probe = 0; probe < 4096; probe++) {     // read-only, L3-hot
            u64 cur = h64[slot];
            if ((unsigned)(cur >> 32) == (unsigned)flat) { rep = (unsigned)cur; break; }
            if (cur == EMPTY64) break;
            slot = (slot + 1u) & HMASK;
        }
        if (rep != 0xFFFFFFFFu) {
            int br = (int)(rep >> 8);                    // rep's 256-block
            int lb = (int)(rep & 255u);
            int dvid = partials[br];
            int wb = br * 4, nw = lb >> 6;
            for (int q = 0; q < nw; q++) dvid += (int)__popcll(flagbits[wb + q]);
            int tail = lb & 63;
            if (tail) dvid += (int)__popcll(flagbits[wb + nw] & ((1ull << tail) - 1ull));
            if (dvid < MAXV) {
                int pos = atomicAdd(&dupcnt[dvid], 1);
                if (pos < MAXP - 1) list[dvid * (MAXP - 1) + pos] = i;
            }
        }
    }
}

// ---- emit: thread-per-row, fully coalesced voxels store; npv ----
__global__ __launch_bounds__(TB) void k_emit(const float4* __restrict__ pts,
                                             const int* __restrict__ repidx,
                                             const int* __restrict__ dupcnt,
                                             const int* __restrict__ list,
                                             float4* __restrict__ outVox,
                                             float* __restrict__ oF) {
    int gid = blockIdx.x * TB + threadIdx.x;
    int vid = gid >> 5;
    if (vid >= MAXV) return;
    int r = gid & 31;
    int ri = repidx[vid];
    int dc = dupcnt[vid];
    int d = dc < (MAXP - 1) ? dc : (MAXP - 1);
    int m = (ri >= 0) ? (1 + d) : 0;
    if (r == 0) oF[OFF_NPV + vid] = (float)m;
    float4 row = make_float4(0.f, 0.f, 0.f, 0.f);
    if (r == 0 && m > 0) {
        row = pts[ri];                               // rep = provably min index
    } else if (r < m) {                              // dup rows, ascending index
        const int* lst = &list[vid * (MAXP - 1)];
        int target = r - 1, pick = -1;
        for (int a = 0; a < d; a++) {
            int e = lst[a];
            int rk = 0;
            for (int bq = 0; bq < d; bq++) rk += (lst[bq] < e);
            if (rk == target) pick = e;
        }
        row = pts[pick];
    }
    outVox[(size_t)vid * MAXP + r] = row;            // coalesced 16B x 64 lanes
}

extern "C" void kernel_launch(void* const* d_in, const int* in_sizes, int n_in,
                              void* d_out, int out_size, void* d_ws, size_t ws_size,
                              hipStream_t stream) {
    int n = in_sizes[0] / 4;                       // 1,200,000
    const float4* pts = (const float4*)d_in[0];

    int tb = TB;
    int nbp = (n + tb - 1) / tb;                   // 4688 (1 pt/thread grids)
    int nwords = nbp * 4;                          // flag words (4 per block)
    int ncw = (n + 63) / 64;                       // contested words

    // ws layout, ~29 MB
    char* base = (char*)d_ws;
    size_t o = 0;
    int* partials = (int*)(base + o);  o += ((size_t)nbp * 4 + 255) & ~(size_t)255;
    int* dupcnt   = (int*)(base + o);  o += (size_t)MAXV * 4;
    int* repidx   = (int*)(base + o);  o += (size_t)MAXV * 4;
    o = (o + 255) & ~(size_t)255;
    u64* flagbits = (u64*)(base + o);  o += (size_t)nwords * 8;
    o = (o + 255) & ~(size_t)255;
    u64* cbits    = (u64*)(base + o);  o += ((size_t)ncw * 8 + 255) & ~(size_t)255;
    u64* h64      = (u64*)(base + o);  o += (size_t)HSIZE * 8;
    int* pflat    = (int*)(base + o);  o += (size_t)n * 4;
    int* list     = (int*)(base + o);  o += (size_t)MAXV * (MAXP - 1) * 4;

    float* oF = (float*)d_out;

    k_init<<<2048, tb, 0, stream>>>(h64, cbits, dupcnt, repidx, n, oF);
    k_build<<<nbp, tb, 0, stream>>>(pts, n, h64, pflat, cbits);
    k_flags<<<nbp, tb, 0, stream>>>(pflat, cbits, n, flagbits, partials);
    k_scan<<<1, 1024, 0, stream>>>(partials, nbp, oF);
    k_finish<<<nbp, tb, 0, stream>>>(flagbits, partials, pflat, h64, repidx, dupcnt, list, n, oF);
    k_emit<<<(MAXV * MAXP + tb - 1) / tb, tb, 0, stream>>>(pts, repidx, dupcnt, list,
                                                           (float4*)d_out, oF);
}

// Round 15
// 139.500 us; speedup vs baseline: 1.6536x; 1.0421x over previous
//
#include <hip/hip_runtime.h>
#include <stdint.h>

// Hard voxelization, MI355X. f32x4 points -> f32 concat out:
//   voxels[60000,32,4], coors[60000,3](z,y,x), npv[60000], voxel_num[1].
//
// Settled forensics (R5-R14):
//  - k_build = one 64B-line device-scope atomic per valid point through the
//    coherence point (~1.4TB/s scattered-line ceiling). ILP-proof (R7);
//    alpha-sensitive (R11 .84 bad / R12 .42 good); read-before-CAS DISPROVEN
//    (R14: pre-reads of atomic-dirtied lines miss all caches -> FETCH 9->58MB,
//    +7us; for atomic-resident data the RMW is the cheapest read).
//  - Mid-pipeline: 1 pt/thread only (R10: serial loops = grid starvation).
//  - NO grid-scale same-line atomics (R13: 4688-block ticket = 104us).
//  - Harness tax (~60us: 256MB ws re-poison + in/out restore) immovable.
// R15 = R12 structure + cbits bitmask, k_build CAS-first. Best-known config.

#define GX 1024
#define GY 1024
#define GZ 40
#define MAXV 60000
#define MAXP 32
#define HBITS 21
#define HSIZE (1u << HBITS)
#define HMASK (HSIZE - 1u)
#define CANDBIT (1 << 30)
#define FLATMASK (CANDBIT - 1)
#define TB 256
#define EMPTY64 0xFFFFFFFFFFFFFFFFull

#define OFF_COORS ((size_t)MAXV * MAXP * 4)            // 7,680,000
#define OFF_NPV   (OFF_COORS + (size_t)MAXV * 3)       // 7,860,000
#define OFF_VNUM  (OFF_NPV + (size_t)MAXV)             // 7,920,000

typedef unsigned long long u64;

__device__ __forceinline__ unsigned hashf(int flat) {
    return ((unsigned)flat * 2654435761u) >> (32 - HBITS);
}

// ---- init: h64=EMPTY(16MB), cbits=0, dupcnt=0, repidx=-1, coors=0 ----
__global__ void k_init(u64* __restrict__ h64, u64* __restrict__ cbits,
                       int* __restrict__ dupcnt, int* __restrict__ repidx,
                       int n, float* __restrict__ oF) {
    int i = blockIdx.x * blockDim.x + threadIdx.x;
    int stride = gridDim.x * blockDim.x;
    for (int j = i; j < (int)HSIZE; j += stride) h64[j] = EMPTY64;
    int ncw = (n + 63) / 64;
    for (int j = i; j < ncw; j += stride) cbits[j] = 0;
    for (int j = i; j < MAXV; j += stride) { dupcnt[j] = 0; repidx[j] = -1; }
    for (int j = i; j < MAXV * 3; j += stride) oF[OFF_COORS + j] = 0.f;
}

__device__ __forceinline__ int voxel_flat(float4 pt) {
    // identical IEEE f32 math to reference
    float fx = floorf((pt.x + 51.2f) / 0.1f);
    float fy = floorf((pt.y + 51.2f) / 0.1f);
    float fz = floorf((pt.z + 5.0f) / 0.2f);
    int cx = (int)fx, cy = (int)fy, cz = (int)fz;
    bool valid = (fx >= 0.f) & (cx < GX) & (fy >= 0.f) & (cy < GY) & (fz >= 0.f) & (cz < GZ);
    return valid ? (cx * GY + cy) * GZ + cz : -1;
}

// ---- build: CAS-first probe (R14 proved read-first regresses) ----
__global__ __launch_bounds__(TB) void k_build(const float4* __restrict__ pts, int n,
                                              u64* __restrict__ h64,
                                              int* __restrict__ pflat,
                                              u64* __restrict__ cbits) {
    int p = blockIdx.x * blockDim.x + threadIdx.x;
    if (p >= n) return;
    float4 pt = pts[p];
    int flat = voxel_flat(pt);
    if (flat < 0) { pflat[p] = -1; return; }
    u64 want = ((u64)(unsigned)flat << 32) | (unsigned)p;
    unsigned slot = hashf(flat);
    int cand = 0;
    for (int probe = 0; probe < 4096; probe++) {          // bounded: hang-proof
        u64 cur = atomicCAS(&h64[slot], EMPTY64, want);
        if (cur == EMPTY64) { cand = 1; break; }          // insert winner
        if ((unsigned)(cur >> 32) == (unsigned)flat) {    // existing voxel
            if ((unsigned)cur > (unsigned)p) {
                u64 old = atomicMin(&h64[slot], want);    // key equal -> compares rep
                unsigned oldrep = (unsigned)old;
                if (oldrep > (unsigned)p) {               // we really lowered it
                    atomicOr(&cbits[oldrep >> 6], 1ull << (oldrep & 63));
                    cand = 1;                             // prev holder dethroned
                }
            }
            break;
        }
        slot = (slot + 1u) & HMASK;
    }
    pflat[p] = flat | (cand ? CANDBIT : 0);
}

// ---- flags: 1 pt/thread; ballot -> flag words + block sums. No loops. ----
__global__ __launch_bounds__(TB) void k_flags(const int* __restrict__ pflat,
                                              const u64* __restrict__ cbits,
                                              int n, u64* __restrict__ flagbits,
                                              int* __restrict__ partials) {
    __shared__ int ws[4];
    int b = blockIdx.x, t = threadIdx.x;
    int i = b * TB + t;
    int pred = 0;
    if (i < n) {
        int pf = pflat[i];
        pred = (pf >= 0) && (pf & CANDBIT) && !((cbits[i >> 6] >> (i & 63)) & 1ull);
    }
    u64 m = __ballot(pred);
    int w = t >> 6, lane = t & 63;
    if (lane == 0) { flagbits[b * 4 + w] = m; ws[w] = __popcll(m); }
    __syncthreads();
    if (t == 0) partials[b] = ws[0] + ws[1] + ws[2] + ws[3];
}

// ---- scan: one 1024-thread block, 5 partials/thread -> exclusive offsets ----
__global__ __launch_bounds__(1024) void k_scan(int* __restrict__ partials, int npart,
                                               float* __restrict__ oF) {
    __shared__ int sh[1024];
    int t = threadIdx.x;
    int v[5];
    int s = 0;
    #pragma unroll
    for (int k = 0; k < 5; k++) {
        int idx = t * 5 + k;
        v[k] = (idx < npart) ? partials[idx] : 0;
        s += v[k];
    }
    sh[t] = s;
    __syncthreads();
    for (int off = 1; off < 1024; off <<= 1) {
        int add = (t >= off) ? sh[t - off] : 0;
        __syncthreads();
        sh[t] += add;
        __syncthreads();
    }
    int run = sh[t] - s;                     // exclusive base for this thread
    #pragma unroll
    for (int k = 0; k < 5; k++) {
        int idx = t * 5 + k;
        if (idx < npart) partials[idx] = run;
        run += v[k];
    }
    if (t == 1023) {
        int total = sh[1023];
        if (total > MAXV) total = MAXV;
        oF[OFF_VNUM] = (float)total;         // voxel_num
    }
}

// ---- finish: 1 pt/thread; vid via popcount rank; reps->coors/repidx,
//      dups(~9K)->h64 re-probe + rank -> dupcnt/list ----
__global__ __launch_bounds__(TB) void k_finish(const u64* __restrict__ flagbits,
                                               const int* __restrict__ partials,
                                               const int* __restrict__ pflat,
                                               const u64* __restrict__ h64,
                                               int* __restrict__ repidx,
                                               int* __restrict__ dupcnt,
                                               int* __restrict__ list, int n,
                                               float* __restrict__ oF) {
    int b = blockIdx.x, t = threadIdx.x;
    int i = b * TB + t;
    if (i >= n) return;
    int lane = t & 63, w = t >> 6;
    u64 w0 = flagbits[b * 4 + 0];
    u64 w1 = flagbits[b * 4 + 1];
    u64 w2 = flagbits[b * 4 + 2];
    u64 w3 = flagbits[b * 4 + 3];
    u64 myw = (w == 0) ? w0 : (w == 1) ? w1 : (w == 2) ? w2 : w3;
    int bit = (int)((myw >> lane) & 1);
    int pf = pflat[i];
    if (bit) {                                           // first occurrence (rep)
        int wbase = (w > 0 ? __popcll(w0) : 0) + (w > 1 ? __popcll(w1) : 0)
                  + (w > 2 ? __popcll(w2) : 0);
        int vid = partials[b] + wbase + (int)__popcll(myw & ((1ull << lane) - 1ull));
        if (vid < MAXV) {
            int flat = pf & FLATMASK;
            int zc = flat % GZ;
            int t2 = flat / GZ;
            int yc = t2 % GY;
            int xc = t2 / GY;
            size_t cOff = OFF_COORS + (size_t)vid * 3;
            oF[cOff + 0] = (float)zc;
            oF[cOff + 1] = (float)yc;
            oF[cOff + 2] = (float)xc;
            repidx[vid] = i;
        }
    } else if (pf >= 0) {                                // non-rep valid (~9K)
        int flat = pf & FLATMASK;
        unsigned slot = hashf(flat);
        unsigned rep = 0xFFFFFFFFu;
        for (int probe = 0; probe < 4096; probe++) {     // read-only, L3-hot
            u64 cur = h64[slot];
            if ((unsigned)(cur >> 32) == (unsigned)flat) { rep = (unsigned)cur; break; }
            if (cur == EMPTY64) break;
            slot = (slot + 1u) & HMASK;
        }
        if (rep != 0xFFFFFFFFu) {
            int br = (int)(rep >> 8);                    // rep's 256-block
            int lb = (int)(rep & 255u);
            int dvid = partials[br];
            int wb = br * 4, nw = lb >> 6;
            for (int q = 0; q < nw; q++) dvid += (int)__popcll(flagbits[wb + q]);
            int tail = lb & 63;
            if (tail) dvid += (int)__popcll(flagbits[wb + nw] & ((1ull << tail) - 1ull));
            if (dvid < MAXV) {
                int pos = atomicAdd(&dupcnt[dvid], 1);
                if (pos < MAXP - 1) list[dvid * (MAXP - 1) + pos] = i;
            }
        }
    }
}

// ---- emit: thread-per-row, fully coalesced voxels store; npv ----
__global__ __launch_bounds__(TB) void k_emit(const float4* __restrict__ pts,
                                             const int* __restrict__ repidx,
                                             const int* __restrict__ dupcnt,
                                             const int* __restrict__ list,
                                             float4* __restrict__ outVox,
                                             float* __restrict__ oF) {
    int gid = blockIdx.x * TB + threadIdx.x;
    int vid = gid >> 5;
    if (vid >= MAXV) return;
    int r = gid & 31;
    int ri = repidx[vid];
    int dc = dupcnt[vid];
    int d = dc < (MAXP - 1) ? dc : (MAXP - 1);
    int m = (ri >= 0) ? (1 + d) : 0;
    if (r == 0) oF[OFF_NPV + vid] = (float)m;
    float4 row = make_float4(0.f, 0.f, 0.f, 0.f);
    if (r == 0 && m > 0) {
        row = pts[ri];                               // rep = provably min index
    } else if (r < m) {                              // dup rows, ascending index
        const int* lst = &list[vid * (MAXP - 1)];
        int target = r - 1, pick = -1;
        for (int a = 0; a < d; a++) {
            int e = lst[a];
            int rk = 0;
            for (int bq = 0; bq < d; bq++) rk += (lst[bq] < e);
            if (rk == target) pick = e;
        }
        row = pts[pick];
    }
    outVox[(size_t)vid * MAXP + r] = row;            // coalesced 16B x 64 lanes
}

extern "C" void kernel_launch(void* const* d_in, const int* in_sizes, int n_in,
                              void* d_out, int out_size, void* d_ws, size_t ws_size,
                              hipStream_t stream) {
    int n = in_sizes[0] / 4;                       // 1,200,000
    const float4* pts = (const float4*)d_in[0];

    int tb = TB;
    int nbp = (n + tb - 1) / tb;                   // 4688 (1 pt/thread grids)
    int nwords = nbp * 4;                          // flag words (4 per block)
    int ncw = (n + 63) / 64;                       // contested words

    // ws layout, ~29 MB
    char* base = (char*)d_ws;
    size_t o = 0;
    int* partials = (int*)(base + o);  o += ((size_t)nbp * 4 + 255) & ~(size_t)255;
    int* dupcnt   = (int*)(base + o);  o += (size_t)MAXV * 4;
    int* repidx   = (int*)(base + o);  o += (size_t)MAXV * 4;
    o = (o + 255) & ~(size_t)255;
    u64* flagbits = (u64*)(base + o);  o += (size_t)nwords * 8;
    o = (o + 255) & ~(size_t)255;
    u64* cbits    = (u64*)(base + o);  o += ((size_t)ncw * 8 + 255) & ~(size_t)255;
    u64* h64      = (u64*)(base + o);  o += (size_t)HSIZE * 8;
    int* pflat    = (int*)(base + o);  o += (size_t)n * 4;
    int* list     = (int*)(base + o);  o += (size_t)MAXV * (MAXP - 1) * 4;

    float* oF = (float*)d_out;

    k_init<<<2048, tb, 0, stream>>>(h64, cbits, dupcnt, repidx, n, oF);
    k_build<<<nbp, tb, 0, stream>>>(pts, n, h64, pflat, cbits);
    k_flags<<<nbp, tb, 0, stream>>>(pflat, cbits, n, flagbits, partials);
    k_scan<<<1, 1024, 0, stream>>>(partials, nbp, oF);
    k_finish<<<nbp, tb, 0, stream>>>(flagbits, partials, pflat, h64, repidx, dupcnt, list, n, oF);
    k_emit<<<(MAXV * MAXP + tb - 1) / tb, tb, 0, stream>>>(pts, repidx, dupcnt, list,
                                                           (float4*)d_out, oF);
}